// Round 11
// baseline (383.801 us; speedup 1.0000x reference)
//
#include <hip/hip_runtime.h>
#include <stdint.h>

#define DEVI __device__ __forceinline__

typedef __bf16 bf16x8 __attribute__((ext_vector_type(8)));
typedef float  floatx4 __attribute__((ext_vector_type(4)));

// B=8, S=2048, H=1024. M = B*S = 16384.
// ws: Q @0 (32MiB, pre-scaled log2e/32) | K @+32M | Vt @+64M ([8][1024 d][2048 k])
//     lvec @+96M (f32[16384]) | P @+96M+64K (bf16 [8][2048][2048]);
//     P region overlays Xb (32MiB) + Wt (6MiB), dead before P written.
//
// Round-16 = round-10 base (370us) + BARRIER-FREE read/MFMA section.
// Timeline model that finally fits r10's counters: per tile per CU, LDS frag
// reads = 192KB (~2260cy) and MFMA = 2060cy were SERIALIZED by the pre-MFMA
// barrier (2260+2060+sync ~= 5250cy measured -> MfmaUtil 39%). This round
// removes that barrier: reads are consumed by each wave's own lgkm-gated
// MFMAs, so waves self-stagger and LDS service overlaps the MFMA pipe.
// Only 2 barriers/tile remain (dbuf safety):
//   [reads+MFMA, no barrier] -> SBAR (all reads retired: every read feeds an
//   MFMA before the barrier) -> stage FULL tile t+2 into cur buf (8 gl_lds)
//   -> WAITV8 (retires tile t+1's 8 stages; per-wave) -> SBAR (whole t+1
//   tile in LDS for everyone) -> next tile reads other buf.
// Tails: t+2>=kI stages nothing -> WAITV0; last tile falls through; one SBAR
// before epilogue restage (fast wave's slice writes vs slow wave's reads).
// Register liveness = r5 (frag peak 64); stage streams advance 1/tile.
// Epilogues/XCD-swizzle/XOR-restage: UNCHANGED from r10 (proven).
// (Kept: no 32x32 MFMA, no B-direct loads; Q carries log2e/32 -> v_exp_f32.)

DEVI unsigned short f2bf(float f) {
  union { float f; uint32_t u; } x; x.f = f;
  return (unsigned short)((x.u + 0x7fffu + ((x.u >> 16) & 1u)) >> 16);
}
DEVI float bf2f(unsigned short s) {
  union { uint32_t u; float f; } x; x.u = ((uint32_t)s) << 16;
  return x.f;
}

// ---------------- fused prep: X->bf16, 3x W transpose->bf16, lvec=0 ----------------
__global__ __launch_bounds__(256) void k_prep(
    const float* __restrict__ X, unsigned short* __restrict__ Xb,
    const float* __restrict__ Wq, const float* __restrict__ Wk,
    const float* __restrict__ Wv, unsigned short* __restrict__ Wt,
    float* __restrict__ lvec) {
  __shared__ float tile[64][65];
  int bx = blockIdx.x, t = threadIdx.x;
  if (bx < 16384) {                 // convert X: 4194304 float4 groups
    int i = bx * 256 + t;
    float4 v = ((const float4*)X)[i];
    ushort4 o;
    o.x = f2bf(v.x); o.y = f2bf(v.y); o.z = f2bf(v.z); o.w = f2bf(v.w);
    ((ushort4*)Xb)[i] = o;
  } else if (bx < 17152) {          // 3 x 256 transpose blocks
    int idx = bx - 16384;
    int sel = idx >> 8, b2 = idx & 255;
    const float* W = sel == 0 ? Wq : (sel == 1 ? Wk : Wv);
    unsigned short* Wo = Wt + ((size_t)sel << 20);
    int h0 = (b2 & 15) * 64, d0 = (b2 >> 4) * 64;
#pragma unroll
    for (int i = 0; i < 16; ++i) {
      int idx2 = i * 256 + t; int r = idx2 >> 6, c = idx2 & 63;
      tile[r][c] = W[(size_t)(h0 + r) * 1024 + d0 + c];
    }
    __syncthreads();
#pragma unroll
    for (int i = 0; i < 16; ++i) {
      int idx2 = i * 256 + t; int r = idx2 >> 6, c = idx2 & 63;
      Wo[(size_t)(d0 + r) * 1024 + h0 + c] = f2bf(tile[c][r]);
    }
  } else {                          // zero lvec (16384 f32)
    float4 z4 = {0.f, 0.f, 0.f, 0.f};
#pragma unroll
    for (int i = 0; i < 16; ++i) ((float4*)lvec)[i * 256 + t] = z4;
  }
}

// ---------------- async 16B global -> LDS ----------------
DEVI void gl_lds16(const unsigned short* gp, const unsigned short* lp) {
  __builtin_amdgcn_global_load_lds(
      (const __attribute__((address_space(1))) void*)gp,
      (__attribute__((address_space(3))) void*)lp, 16, 0, 0);
}

// Stage one half-tile from persistent streams; advance streams +128B (+1 K-tile).
#define STAGE_A(q, BUF)                                                       \
  do {                                                                        \
    gl_lds16(gA[q][0], AsF + (BUF) + dA[q][0]);                               \
    gl_lds16(gA[q][1], AsF + (BUF) + dA[q][1]);                               \
    gA[q][0] += 64; gA[q][1] += 64;                                           \
  } while (0)
#define STAGE_B(q, BUF)                                                       \
  do {                                                                        \
    gl_lds16(gB[q][0], BsF + (BUF) + dB[q][0]);                               \
    gl_lds16(gB[q][1], BsF + (BUF) + dB[q][1]);                               \
    gB[q][0] += 64; gB[q][1] += 64;                                           \
  } while (0)

// Fragment loads: base ptr + compile-time immediate only.
#define READ_A(MH)                                                            \
  _Pragma("unroll") for (int ms = 0; ms < 4; ++ms) {                          \
    af[0][ms] = *(const bf16x8*)(pA0 + (MH) * 8192 + ms * 2048);              \
    af[1][ms] = *(const bf16x8*)(pA1 + (MH) * 8192 + ms * 2048);              \
  }
#define READ_B(DST, NH)                                                       \
  _Pragma("unroll") for (int ns = 0; ns < 2; ++ns) {                          \
    DST[0][ns] = *(const bf16x8*)(pB0 + (NH) * 4096 + ns * 2048);             \
    DST[1][ns] = *(const bf16x8*)(pB1 + (NH) * 4096 + ns * 2048);             \
  }

// 16 MFMAs for one C-quadrant (no setprio; caller wraps the cluster).
#define MFMA_Q(MH, NH, BSET)                                                  \
  _Pragma("unroll") for (int kk = 0; kk < 2; ++kk)                            \
  _Pragma("unroll") for (int ms = 0; ms < 4; ++ms)                            \
  _Pragma("unroll") for (int ns = 0; ns < 2; ++ns)                            \
    acc[(MH) * 4 + ms][(NH) * 2 + ns] =                                       \
        __builtin_amdgcn_mfma_f32_16x16x32_bf16(                              \
            af[kk][ms], BSET[kk][ns], acc[(MH) * 4 + ms][(NH) * 2 + ns],      \
            0, 0, 0);

#define PRIO1 __builtin_amdgcn_s_setprio(1)
#define PRIO0 __builtin_amdgcn_s_setprio(0)
#define WAITV8 asm volatile("s_waitcnt vmcnt(8)" ::: "memory")
#define WAITV0 asm volatile("s_waitcnt vmcnt(0)" ::: "memory")
#define SBAR __builtin_amdgcn_s_barrier()

// ---------------- C = A * Bt^T  (both bf16 row-major, K-major rows) ----------------
// 256x256 tile, BK=64, 8 waves (2M x 4N, 128x64 each), 128KiB dbuf LDS.
// EPI: 4 = fused QKV (sel=blockIdx.y>>2): Q (x+b)*log2e/32, K x+b, V -> Vt[b][d][k]
//      2 = P = 2^S masked, bf16; atomic row sums -> lsum
//      3 = O = (P*V) * 1/lvec[row], f32
template <int EPI>
__global__ __launch_bounds__(512, 2) void k_gemm(
    const unsigned short* __restrict__ A, const unsigned short* __restrict__ Bt,
    void* __restrict__ Cv,
    const float* __restrict__ bias_q, const float* __restrict__ bias_k,
    const float* __restrict__ bias_v,
    const float* __restrict__ lvec, float* __restrict__ lsum,
    const int* __restrict__ mask,
    long aZ, long bZ, int ldA, int ldB, int kIters)
{
  // Single contiguous 128KB LDS block. A-buffers at [0, 32768) ushorts,
  // B-buffers at [32768, 65536). One buffer = 256x64 bf16 = 16384 ushorts;
  // BUF stride 16384. Epilogue reuses the block as 8 x 16KB wave slices.
  __shared__ __attribute__((aligned(16))) unsigned short LDSu[4 * 256 * 64];
  unsigned short* const AsF = LDSu;
  unsigned short* const BsF = LDSu + 2 * 256 * 64;
  const int tid = threadIdx.x, w = tid >> 6, l = tid & 63;
  const int quad = l >> 4, l15 = l & 15;
  const int wr = w & 1, wc = w >> 1;           // 2M x 4N wave grid
  const int wm = wr * 128, wn = wc * 64;

  // ---- bijective rect XCD swizzle (EPI2: 4x2 rects/z; EPI3: 2x2) ----
  int bx = blockIdx.x, by = blockIdx.y, bz = blockIdx.z;
  if constexpr (EPI == 2) {              // grid (8,8,8)
    int lin = bx + (by << 3) + (bz << 6);
    int xcd = lin & 7, slot = lin >> 3;  // 8 blocks per xcd per z
    bx = ((xcd & 1) << 2) + (slot & 3);
    by = ((xcd >> 1) << 1) + ((slot >> 2) & 1);
    bz = slot >> 3;
  } else if constexpr (EPI == 3) {       // grid (8,4,8)
    int lin = bx + (by << 3) + (bz << 5);
    int xcd = lin & 7, slot = lin >> 3;  // 4 blocks per xcd per z
    bx = ((xcd & 3) << 1) + (slot & 1);
    by = ((xcd >> 2) << 1) + ((slot >> 1) & 1);
    bz = slot >> 2;
  }
  const int m0 = bx * 256;
  const int z = bz;

  int n0, sel = 0;
  if constexpr (EPI == 4) { sel = by >> 2; n0 = (by & 3) * 256; }
  else n0 = by * 256;

  const unsigned short* Az = A + (size_t)z * aZ;
  const unsigned short* Bz = (EPI == 4) ? (Bt + ((size_t)sel << 20))
                                        : (Bt + (size_t)z * bZ);

  // ---- hoisted stage streams: per-lane swizzled global addrs + LDS offsets ----
  const int lr = l >> 3, uu = (l & 7) ^ lr;    // stage swizzle (row bases %8==0)
  const unsigned short* gA[2][2]; const unsigned short* gB[2][2];
  int dA[2][2], dB[2][2];
#pragma unroll
  for (int q = 0; q < 2; ++q)
#pragma unroll
    for (int j = 0; j < 2; ++j) {
      int slot = w * 2 + j;
      int rA = (slot >> 3) * 128 + q * 64 + (slot & 7) * 8;
      int rB = (slot >> 2) * 64 + q * 32 + (slot & 3) * 8;
      gA[q][j] = Az + (size_t)(m0 + rA + lr) * ldA + uu * 8;
      gB[q][j] = Bz + (size_t)(n0 + rB + lr) * ldB + uu * 8;
      dA[q][j] = rA * 64; dB[q][j] = rB * 64;
    }

  // ---- hoisted fragment-read byte offsets (frag swizzle (rr&7)==l15&7) ----
  const int cc0 = quad ^ (l15 & 7), cc1 = cc0 ^ 4;
  const int aoffA0 = (wm + l15) * 128 + cc0 * 16;
  const int aoffA1 = (wm + l15) * 128 + cc1 * 16;
  const int aoffB0 = (wn + l15) * 128 + cc0 * 16;
  const int aoffB1 = (wn + l15) * 128 + cc1 * 16;

  floatx4 acc[8][4];
#pragma unroll
  for (int i = 0; i < 8; ++i)
#pragma unroll
    for (int j = 0; j < 4; ++j) { floatx4 zz = {0.f, 0.f, 0.f, 0.f}; acc[i][j] = zz; }

  // -------- prologue: stage tile0 -> buf0, tile1 -> buf1; tile0 landed ------
  STAGE_A(0, 0); STAGE_A(1, 0); STAGE_B(0, 0); STAGE_B(1, 0);       // t0
  if (kIters > 1) {
    STAGE_A(0, 16384); STAGE_A(1, 16384);                            // t1
    STAGE_B(0, 16384); STAGE_B(1, 16384);
    WAITV8;                       // 8 newest = t1's; retires all of t0
  } else {
    WAITV0;
  }
  SBAR;

  // -------- main loop: barrier-free reads+MFMA, 2 barriers/tile ------------
#pragma unroll 2
  for (int kt = 0; kt < kIters; ++kt) {
    const int ob = (kt & 1) ? 16384 : 0;   // current buffer (ushort offset)
    const char* pA0 = (const char*)(AsF + ob) + aoffA0;
    const char* pA1 = (const char*)(AsF + ob) + aoffA1;
    const char* pB0 = (const char*)(BsF + ob) + aoffB0;
    const char* pB1 = (const char*)(BsF + ob) + aoffB1;
    bf16x8 af[2][4], bfr0[2][2], bfr1[2][2];

    // reads + MFMA, no barriers: each read is consumed by an lgkm-gated MFMA
    // below, so waves self-stagger and LDS service overlaps the MFMA pipe.
    READ_A(0); READ_B(bfr0, 0); READ_B(bfr1, 1);
    PRIO1;
    MFMA_Q(0, 0, bfr0);
    MFMA_Q(0, 1, bfr1);
    PRIO0;
    READ_A(1);                              // af dead after Q01 -> reuse
    PRIO1;
    MFMA_Q(1, 1, bfr1);
    MFMA_Q(1, 0, bfr0);
    PRIO0;

    // dbuf sync section (skipped entirely on the last tile)
    if (kt + 2 < kIters) {
      SBAR;                                 // all waves done reading buf ob
      STAGE_A(0, ob); STAGE_A(1, ob);       // stage tile t+2 -> buf ob
      STAGE_B(0, ob); STAGE_B(1, ob);
      WAITV8;                               // retires tile t+1's 8 stages
      SBAR;                                 // whole t+1 tile visible to all
    } else if (kt + 1 < kIters) {
      SBAR;
      WAITV0;                               // retires tile t+1's stages
      SBAR;
    }
  }
  SBAR;  // epilogue guard: slowest wave's last-tile reads vs slice restage

  // ---- epilogues. C/D layout col = lane&15, row = quad*4 + reg  [m89/m91].
  // Each wave restages its output in its private 16KB slice (LDSu + w*8192).
  // Row-XOR chunk placement on write+read keeps global addressing unchanged
  // while killing scalar-write bank conflicts (r10: 4.98M -> 262K).
  if constexpr (EPI == 4) {
    unsigned short* C = (unsigned short*)Cv + ((size_t)sel << 24);
    const float* bs = sel == 0 ? bias_q : (sel == 1 ? bias_k : bias_v);
    unsigned short* sl = LDSu + w * 8192;
    if (sel < 2) {
      // slice [128 rows(m)][64 cols(n)]; 8 chunks/row; XOR arg row&7.
      float sc = sel == 0 ? 0.045084439f : 1.0f;   // log2e/32
#pragma unroll
      for (int ns = 0; ns < 4; ++ns) {
        int n_g = n0 + wn + ns * 16 + l15;
        float bv = bs[n_g];
        int c8 = ns * 2 + (l15 >> 3);       // logical chunk of col ns*16+l15
#pragma unroll
        for (int ms = 0; ms < 8; ++ms) {
#pragma unroll
          for (int r = 0; r < 4; ++r) {
            int row = ms * 16 + quad * 4 + r;
            int ph = c8 ^ (row & 7);
            sl[row * 64 + ph * 8 + (l15 & 7)] = f2bf((acc[ms][ns][r] + bv) * sc);
          }
        }
      }
#pragma unroll
      for (int i = 0; i < 16; ++i) {
        int row = i * 8 + lr;
        bf16x8 v = *(const bf16x8*)&sl[row * 64 + ((l & 7) ^ lr) * 8];
        *(bf16x8*)&C[(size_t)(m0 + wm + row) * 1024 + n0 + wn + (l & 7) * 8] = v;
      }
    } else {
      // Vt slice [64 rows(d)][128 cols(key)]; 16 chunks/row; XOR arg row&15
      // (= l15 on write). ushort4 = half-chunk, offset (quad&1)*4.
#pragma unroll
      for (int ns = 0; ns < 4; ++ns) {
        int n_g = n0 + wn + ns * 16 + l15;
        float bv = bs[n_g];
        int row = ns * 16 + l15;
#pragma unroll
        for (int ms = 0; ms < 8; ++ms) {
          ushort4 pk;
          pk.x = f2bf(acc[ms][ns][0] + bv);
          pk.y = f2bf(acc[ms][ns][1] + bv);
          pk.z = f2bf(acc[ms][ns][2] + bv);
          pk.w = f2bf(acc[ms][ns][3] + bv);
          int ph = (ms * 2 + (quad >> 1)) ^ l15;   // ^(row&15), row&15==l15
          *(ushort4*)&sl[row * 128 + ph * 8 + (quad & 1) * 4] = pk;
        }
      }
      const size_t vbase = ((size_t)(m0 >> 11) << 21) + (size_t)((m0 & 2047) + wm);
#pragma unroll
      for (int i = 0; i < 16; ++i) {
        int row = i * 4 + quad;
        int ph = (l & 15) ^ (row & 15);
        bf16x8 v = *(const bf16x8*)&sl[row * 128 + ph * 8];
        int drow = n0 + wn + row;
        *(bf16x8*)&C[vbase + ((size_t)drow << 11) + (l & 15) * 8] = v;
      }
    }
  } else if constexpr (EPI == 2) {
    // P = 2^S (S pre-scaled by log2e; max-free), masked; atomic rowsums.
    unsigned short* C = (unsigned short*)Cv + (size_t)z * 4194304;
    const int* mz = mask + z * 2048;
    unsigned short* sl = LDSu + w * 8192;  // slice [128 m][64 n], XOR row&7
    float rowsum[8][4];
#pragma unroll
    for (int ms = 0; ms < 8; ++ms)
#pragma unroll
      for (int r = 0; r < 4; ++r) rowsum[ms][r] = 0.f;
#pragma unroll
    for (int ns = 0; ns < 4; ++ns) {
      int n_g = n0 + wn + ns * 16 + l15;
      int mv = mz[n_g];
      int c8 = ns * 2 + (l15 >> 3);
#pragma unroll
      for (int ms = 0; ms < 8; ++ms) {
#pragma unroll
        for (int r = 0; r < 4; ++r) {
          int row = ms * 16 + quad * 4 + r;
          float e;
          asm("v_exp_f32 %0, %1" : "=v"(e) : "v"(acc[ms][ns][r]));  // 2^x
          e = mv ? e : 0.f;
          unsigned short pb = f2bf(e);
          int ph = c8 ^ (row & 7);
          sl[row * 64 + ph * 8 + (l15 & 7)] = pb;
          rowsum[ms][r] += bf2f(pb);
        }
      }
    }
#pragma unroll
    for (int ms = 0; ms < 8; ++ms) {
#pragma unroll
      for (int r = 0; r < 4; ++r) {
        float s = rowsum[ms][r];
#pragma unroll
        for (int off = 1; off < 16; off <<= 1) s += __shfl_xor(s, off);
        if (l15 == 0) {
          int m_g = m0 + wm + ms * 16 + quad * 4 + r;
          atomicAdd(&lsum[z * 2048 + m_g], s);
        }
      }
    }
#pragma unroll
    for (int i = 0; i < 16; ++i) {
      int row = i * 8 + lr;
      bf16x8 v = *(const bf16x8*)&sl[row * 64 + ((l & 7) ^ lr) * 8];
      *(bf16x8*)&C[(size_t)(m0 + wm + row) * 2048 + n0 + wn + (l & 7) * 8] = v;
    }
  } else {  // EPI == 3: O = (P*V)/l, f32 — restaged in two 16KB halves.
    float* C = (float*)Cv + (size_t)z * 2048 * 1024;
    const float* lz = lvec + z * 2048;
    float* slf = (float*)(LDSu) + w * 4096;   // 16KB: [64 rows][64 f32]
#pragma unroll
    for (int half = 0; half < 2; ++half) {
      // write: 16 chunks(4xf32)/row; XOR arg row&15 (= quad*4+r).
#pragma unroll
      for (int ms4 = 0; ms4 < 4; ++ms4) {
        int ms = half * 4 + ms4;
#pragma unroll
        for (int r = 0; r < 4; ++r) {
          int row = ms4 * 16 + quad * 4 + r;
          int m_g = m0 + wm + half * 64 + row;
          float lw = lz[m_g];
          float inv = lw > 0.f ? 1.f / lw : 0.f;
#pragma unroll
          for (int ns = 0; ns < 4; ++ns) {
            int ph = (ns * 4 + (l15 >> 2)) ^ (quad * 4 + r);
            slf[row * 64 + ph * 4 + (l15 & 3)] = acc[ms][ns][r] * inv;
          }
        }
      }
      // read + 16B stores (256B contiguous per 16-lane group)
#pragma unroll
      for (int i = 0; i < 16; ++i) {
        int row = i * 4 + quad;
        int ph = (l & 15) ^ (row & 15);
        floatx4 v = *(const floatx4*)&slf[row * 64 + ph * 4];
        int m_g = m0 + wm + half * 64 + row;
        *(floatx4*)&C[(size_t)m_g * 1024 + n0 + wn + (l & 15) * 4] = v;
      }
    }
  }
}

extern "C" void kernel_launch(void* const* d_in, const int* in_sizes, int n_in,
                              void* d_out, int out_size, void* d_ws, size_t ws_size,
                              hipStream_t stream) {
  const float* X    = (const float*)d_in[0];
  const int*   mask = (const int*)d_in[1];
  const float* Wq   = (const float*)d_in[2];
  const float* bq   = (const float*)d_in[3];
  const float* Wk   = (const float*)d_in[4];
  const float* bk   = (const float*)d_in[5];
  const float* Wv   = (const float*)d_in[6];
  const float* bv   = (const float*)d_in[7];
  float* out = (float*)d_out;

  constexpr size_t SZ = (size_t)16384 * 1024;
  unsigned short* Q    = (unsigned short*)d_ws;      // Q|K|Vt contiguous (sel<<24)
  float*          lvec = (float*)(Q + 3 * SZ);
  unsigned short* P    = (unsigned short*)(lvec + 16384);
  unsigned short* Xb   = P;               // overlaid: dead before P written
  unsigned short* Wt   = Xb + SZ;         // 3 x [1024][1024] bf16
  unsigned short* Vt   = Q + 2 * SZ;

  // 1. prep: X->bf16, W->Wt (bf16, transposed), lvec=0
  k_prep<<<dim3(17153), 256, 0, stream>>>(X, Xb, Wq, Wk, Wv, Wt, lvec);

  // 2. fused QKV projection (12 n-strips: 4 Q, 4 K, 4 V)
  k_gemm<4><<<dim3(64, 12, 1), 512, 0, stream>>>(
      Xb, Wt, (void*)Q, bq, bk, bv, nullptr, nullptr, nullptr,
      0, 0, 1024, 1024, 16);

  // 3. P = 2^(Q K^T * log2e/32) masked + atomic row sums
  k_gemm<2><<<dim3(8, 8, 8), 512, 0, stream>>>(
      Q, Q + SZ, (void*)P, nullptr, nullptr, nullptr, nullptr, lvec, mask,
      2048 * 1024, 2048 * 1024, 1024, 1024, 16);

  // 4. O = (P V) / l  -> fp32 out
  k_gemm<3><<<dim3(8, 4, 8), 512, 0, stream>>>(
      P, Vt, (void*)out, nullptr, nullptr, nullptr, lvec, nullptr, nullptr,
      2048 * 2048, 1024 * 2048, 2048, 2048, 32);
}